// Round 4
// baseline (723.882 us; speedup 1.0000x reference)
//
#include <hip/hip_runtime.h>
#include <cstdint>
#include <cstddef>

// Problem constants
#define MROWS 8192   // B*C = 32*256
#define VIN   6890   // K (real)
#define VOUT  1723   // N (real)
#define KP    6912   // K padded to multiple of 32 (216 * 32)
#define NP    1792   // N padded to multiple of 128 (14 * 128)
#define NKB   (KP / 32)   // 216 K-iterations
#define NBN   (NP / 128)  // 14 column tiles
#define NBM   (MROWS / 128) // 64 row tiles

typedef __attribute__((ext_vector_type(8))) __bf16 bf16x8;  // 4 VGPRs, A/B frag
typedef __attribute__((ext_vector_type(4))) float f32x4;    // C/D frag

// ---------------- fp32 -> bf16 (RNE) ----------------
__device__ __forceinline__ uint32_t f2bf(float f) {
    uint32_t u = __builtin_bit_cast(uint32_t, f);
    u += 0x7fffu + ((u >> 16) & 1u);
    return u >> 16;
}

// x: [MROWS][VIN] fp32 -> xb: [MROWS][KP] bf16 (zero-padded K tail)
__global__ __launch_bounds__(256) void cvt_x_kernel(
        const float* __restrict__ x, uint16_t* __restrict__ xb) {
    const int row = blockIdx.y;
    const int g   = blockIdx.x * blockDim.x + threadIdx.x;  // 8-float group
    if (g >= KP / 8) return;
    const int c = g * 8;
    uint32_t w[4];
#pragma unroll
    for (int p = 0; p < 4; ++p) {
        const int cc = c + p * 2;
        float2 f = make_float2(0.f, 0.f);
        if (cc < VIN)  // VIN even -> pair fully valid or fully pad
            f = *(const float2*)(x + (size_t)row * VIN + cc);
        w[p] = f2bf(f.x) | (f2bf(f.y) << 16);
    }
    uint4 o; o.x = w[0]; o.y = w[1]; o.z = w[2]; o.w = w[3];
    *(uint4*)(xb + (size_t)row * KP + c) = o;
}

// M: [VOUT][VIN] fp32 -> mb: [NP][KP] bf16 (zero-padded rows & K tail)
__global__ __launch_bounds__(256) void cvt_m_kernel(
        const float* __restrict__ m, uint16_t* __restrict__ mb) {
    const int row = blockIdx.y;
    const int g   = blockIdx.x * blockDim.x + threadIdx.x;
    if (g >= KP / 8) return;
    const int c = g * 8;
    uint32_t w[4];
    const bool rv = (row < VOUT);
#pragma unroll
    for (int p = 0; p < 4; ++p) {
        const int cc = c + p * 2;
        float2 f = make_float2(0.f, 0.f);
        if (rv && cc < VIN)
            f = *(const float2*)(m + (size_t)row * VIN + cc);
        w[p] = f2bf(f.x) | (f2bf(f.y) << 16);
    }
    uint4 o; o.x = w[0]; o.y = w[1]; o.z = w[2]; o.w = w[3];
    *(uint4*)(mb + (size_t)row * KP + c) = o;
}

// ---------------- async global -> LDS, 16B/lane ----------------
__device__ __forceinline__ void gload_lds16(const void* g, void* l) {
    __builtin_amdgcn_global_load_lds(
        (const __attribute__((address_space(1))) void*)g,
        (__attribute__((address_space(3))) void*)l,
        16, 0, 0);
}

// ---------------- bf16 MFMA GEMM: C[m,n] = sum_k X[m,k] * W[n,k] ----------------
// 128x128 tile, 4 waves 2x2, each wave 4x4 of 16x16x32 MFMA.
// Round-4 changes vs m97 structure:
//  * DOUBLE-BUFFERED LDS with cross-barrier DMA prefetch: tile k+1's
//    global_load_lds is issued right after the barrier that drained tile k's,
//    so the vmcnt(0) drain at the NEXT barrier waits on a DMA that has had a
//    full iteration (~300+ cyc of MFMA + ds_read) to complete. Also: ONE
//    barrier per K-iter instead of two.
//  * XCD-PINNED BLOCK SWIZZLE: 1D grid; xcd = id&7 picks the XCD (round-robin
//    dispatch heuristic), each XCD owns 8 bm-strips with bn innermost, so
//    concurrently-resident blocks on an XCD share the same A-strips -> xb
//    L2-fills drop from ~4.3x to ~1x and staging latency is L2-class.
//  * Bank-conflict source-side swizzle kept from round 3 (conflicts == 0).
__global__ __launch_bounds__(256) void gemm_bt_kernel(
        const uint16_t* __restrict__ X,    // [MROWS][KP] bf16 bits
        const uint16_t* __restrict__ W,    // [NP][KP]   bf16 bits
        float* __restrict__ out) {         // [MROWS][VOUT] fp32
    __shared__ uint16_t lsA[2 * 4096];  // 16 KB (double-buffered)
    __shared__ uint16_t lsB[2 * 4096];  // 16 KB

    const int t    = threadIdx.x;
    const int wave = t >> 6;
    const int lane = t & 63;
    const int wm   = wave >> 1;   // 0..1
    const int wn   = wave & 1;    // 0..1

    // XCD-pinned tile mapping (64 bm x 14 bn = 896 blocks; 112 per XCD)
    const int l   = blockIdx.x;
    const int xcd = l & 7;
    const int li  = l >> 3;        // 0..111
    const int bn  = li % NBN;      // innermost: 14 blocks share one A-strip
    const int bm  = (li / NBN) * 8 + xcd;

    // staging coords: 256 threads cover 64 rows x 64 bytes per issue
    const int srow  = t >> 2;                               // 0..63
    const int row16 = srow & 15;                            // row in wave's chunk
    const int sbyte = ((t & 3) ^ ((row16 >> 1) & 3)) * 16;  // swizzled granule

    const char* gA = (const char*)(X + (size_t)(bm * 128 + srow) * KP) + sbyte;
    const char* gB = (const char*)(W + (size_t)(bn * 128 + srow) * KP) + sbyte;
    const size_t gRow64 = (size_t)64 * KP * 2;  // 64 rows in bytes

    // compute coords (16x16x32 A/B frag: row/col = lane&15, k = (lane>>4)*8 + j)
    const int m15  = lane & 15;
    const int gsel = ((lane >> 4) ^ ((m15 >> 1) & 3)) * 8;  // swizzled ushort off

    f32x4 acc[4][4] = {};

    // prologue: prefetch tile 0 into buffer 0
    {
        uint16_t* a0 = &lsA[wave * 512];
        uint16_t* b0 = &lsB[wave * 512];
        gload_lds16(gA, a0);
        gload_lds16(gA + gRow64, a0 + 2048);
        gload_lds16(gB, b0);
        gload_lds16(gB + gRow64, b0 + 2048);
    }

    for (int kb = 0; kb < NKB; ++kb) {
        const int cur = kb & 1;
        __syncthreads();  // drains DMA into `cur` (issued one full iter ago)

        if (kb + 1 < NKB) {  // prefetch tile kb+1 into the other buffer
            const size_t koff = (size_t)(kb + 1) * 64;
            uint16_t* a0 = &lsA[(cur ^ 1) * 4096 + wave * 512];
            uint16_t* b0 = &lsB[(cur ^ 1) * 4096 + wave * 512];
            gload_lds16(gA + koff,          a0);
            gload_lds16(gA + gRow64 + koff, a0 + 2048);
            gload_lds16(gB + koff,          b0);
            gload_lds16(gB + gRow64 + koff, b0 + 2048);
        }

        const uint16_t* A = &lsA[cur * 4096];
        const uint16_t* B = &lsB[cur * 4096];
        bf16x8 a[4], b[4];
#pragma unroll
        for (int i = 0; i < 4; ++i) {
            a[i] = *(const bf16x8*)&A[(wm * 64 + i * 16 + m15) * 32 + gsel];
            b[i] = *(const bf16x8*)&B[(wn * 64 + i * 16 + m15) * 32 + gsel];
        }
#pragma unroll
        for (int i = 0; i < 4; ++i)
#pragma unroll
            for (int j = 0; j < 4; ++j)
                acc[i][j] = __builtin_amdgcn_mfma_f32_16x16x32_bf16(
                    a[i], b[j], acc[i][j], 0, 0, 0);
        // no second barrier: next iteration's barrier protects buffer reuse
        // (prefetch into buf `cur^1` only happens after the barrier that
        //  guaranteed all reads of `cur^1` from iter kb-1 completed)
    }

    // epilogue: C/D layout col = lane&15, row = (lane>>4)*4 + reg  [m89/m91]
    const int row0 = bm * 128 + wm * 64 + (lane >> 4) * 4;
    const int col0 = bn * 128 + wn * 64 + m15;
#pragma unroll
    for (int j = 0; j < 4; ++j) {
        const int col = col0 + j * 16;
        if (col < VOUT) {
#pragma unroll
            for (int i = 0; i < 4; ++i) {
                const int rowb = row0 + i * 16;
#pragma unroll
                for (int r = 0; r < 4; ++r)
                    out[(size_t)(rowb + r) * VOUT + col] = acc[i][j][r];
            }
        }
    }
}

// ---------------- fp32 fallback (only if ws too small) ----------------
__global__ void fallback_kernel(const float* __restrict__ x,
                                const float* __restrict__ M,
                                float* __restrict__ out) {
    const int m = blockIdx.y;
    const int o = blockIdx.x * blockDim.x + threadIdx.x;
    if (o >= VOUT) return;
    const float* xr = x + (size_t)m * VIN;
    const float* mr = M + (size_t)o * VIN;
    float s = 0.f;
    for (int k = 0; k < VIN; ++k) s = fmaf(xr[k], mr[k], s);
    out[(size_t)m * VOUT + o] = s;
}

extern "C" void kernel_launch(void* const* d_in, const int* in_sizes, int n_in,
                              void* d_out, int out_size, void* d_ws, size_t ws_size,
                              hipStream_t stream) {
    const float* x = (const float*)d_in[0];
    const float* M = (const float*)d_in[1];
    float* out = (float*)d_out;

    const size_t need = ((size_t)MROWS * KP + (size_t)NP * KP) * sizeof(uint16_t);
    if (ws_size < need) {
        fallback_kernel<<<dim3((VOUT + 255) / 256, MROWS), dim3(256), 0, stream>>>(x, M, out);
        return;
    }

    uint16_t* xb = (uint16_t*)d_ws;
    uint16_t* mb = xb + (size_t)MROWS * KP;

    const dim3 cblk(256);
    const int gx = (KP / 8 + 255) / 256;  // 4
    cvt_x_kernel<<<dim3(gx, MROWS), cblk, 0, stream>>>(x, xb);
    cvt_m_kernel<<<dim3(gx, NP),    cblk, 0, stream>>>(M, mb);

    gemm_bt_kernel<<<dim3(NBM * NBN), dim3(256), 0, stream>>>(xb, mb, out);
}